// Round 13
// baseline (278.385 us; speedup 1.0000x reference)
//
#include <hip/hip_runtime.h>
#include <hip/hip_bf16.h>

// ---------------------------------------------------------------------------
// MOF_Net: DGCN(graph2) -> e_t ; MOLGCN(graph1) -> h ; global add pool /2
// N1=20000, E1=640000, N2=640000(==E1), E2=1280000
// Round 13: rank-ordered e_t (R11's sound half, no payload): csr1 emits
// rank1[e]; csr2 keys graph-2 records by rank1[d]; msg2 writes e_t at key
// (random 64B sectors); msg1 reads e_t sequentially. Epilogue unchanged.
// ---------------------------------------------------------------------------

#define NUM_GRAPHS 64
#define CAP 4608        // per-bucket capacity (mean ~4090, +8 sigma)
#define CURSTRIDE 16    // ints per cursor (64B line padding)
#define EPB 8192        // edges per bscat block
#define NCVT 2048       // cvt role blocks in fused kernel

typedef __attribute__((ext_vector_type(8))) short bf16x8;
typedef __attribute__((ext_vector_type(4))) float f32x4;

__device__ __forceinline__ unsigned short f2bf(float x) {
    __hip_bfloat16 b = __float2bfloat16(x);
    return *(unsigned short*)&b;
}
__device__ __forceinline__ float bf2f(unsigned int u16) {
    unsigned short us = (unsigned short)u16;
    __hip_bfloat16 b = *(__hip_bfloat16*)&us;
    return __bfloat162float(b);
}
__device__ __forceinline__ unsigned int pack2(float lo, float hi) {
    return (unsigned int)f2bf(lo) | ((unsigned int)f2bf(hi) << 16);
}
__device__ __forceinline__ uint4 cvt8(const float* src) {
    const float4* s4 = (const float4*)src;
    float4 a = s4[0], b = s4[1];
    return make_uint4(pack2(a.x, a.y), pack2(a.z, a.w),
                      pack2(b.x, b.y), pack2(b.z, b.w));
}
__device__ __forceinline__ int swz(int row, int kb) {
    return row * 128 + (kb ^ ((row & 7) << 4));
}

// ---------------- prep0: pack weight images + zero bucket cursors ----------

__global__ __launch_bounds__(256) void k_prep0(
    const float* __restrict__ W2a, const float* __restrict__ b2a,
    const float* __restrict__ W2b, const float* __restrict__ b2b,
    const float* __restrict__ W1a, const float* __restrict__ b1a,
    const float* __restrict__ W1b, const float* __restrict__ b1b,
    unsigned char* __restrict__ wpack, int* __restrict__ cur, int ncur)
{
    const int tid = threadIdx.x;
    if (blockIdx.x == 0) {
        unsigned char* img1 = wpack;
        unsigned char* img2 = wpack + 12672;
        for (int i = tid; i < 64 * 64; i += 256) {
            int n = i >> 6, k = i & 63;
            float v1 = (k < 48) ? W2a[k * 64 + n] : 0.0f;
            *(unsigned short*)(img1 + n * 128 + ((2 * k) ^ ((n & 7) << 4))) = f2bf(v1);
            *(unsigned short*)(img2 + n * 128 + ((2 * k) ^ ((n & 7) << 4))) = f2bf(W1a[k * 64 + n]);
        }
        for (int i = tid; i < 32 * 64; i += 256) {
            int n = i >> 6, k = i & 63;
            *(unsigned short*)(img1 + 8192 + n * 128 + ((2 * k) ^ ((n & 7) << 4))) = f2bf(W2b[k * 32 + n]);
            *(unsigned short*)(img2 + 8192 + n * 128 + ((2 * k) ^ ((n & 7) << 4))) = f2bf(W1b[k * 32 + n]);
        }
        if (tid < 64) {
            ((float*)(img1 + 12288))[tid] = b2a[tid];
            ((float*)(img2 + 12288))[tid] = b1a[tid];
        }
        if (tid < 32) {
            ((float*)(img1 + 12544))[tid] = b2b[tid];
            ((float*)(img2 + 12544))[tid] = b1b[tid];
        }
    } else {
        for (int i = tid; i < ncur; i += 256) cur[i] = 0;
    }
}

// ---------------- fused: bucket scatter (block-claimed runs) + cvt ---------
// mid record: x = e | (dlo<<21), y = s

__global__ __launch_bounds__(256) void k_bscat_cvt(
    const int* __restrict__ ei2, int E2, const int* __restrict__ ei1, int E1,
    int* __restrict__ cur, uint2* __restrict__ mid, int NB2, int NBT, int Etot, int NBB,
    const float* __restrict__ x2, uint4* __restrict__ x2b,
    const float* __restrict__ x1, uint4* __restrict__ x1b,
    const float* __restrict__ ea2, uint4* __restrict__ ea2b,
    long xn2, long xn1, long xne)
{
    __shared__ unsigned int buck[EPB];   // b | dlo<<16
    __shared__ int hist[512];
    __shared__ int gbase[512];
    __shared__ int wloc[512];

    const int tid = threadIdx.x;
    if (blockIdx.x >= NBB) {
        const long tot = xn2 + xn1 + xne;
        const long stride = (long)NCVT * 256;
        for (long i = (long)(blockIdx.x - NBB) * 256 + tid; i < tot; i += stride) {
            if (i < xn2) x2b[i] = cvt8(x2 + i * 8);
            else if (i < xn2 + xn1) { long j = i - xn2; x1b[j] = cvt8(x1 + j * 8); }
            else { long j = i - xn2 - xn1; ea2b[j] = cvt8(ea2 + j * 8); }
        }
        return;
    }

    const long start = (long)blockIdx.x * EPB;
    const int nloc = (int)(((long)Etot - start) < EPB ? ((long)Etot - start) : EPB);
    if (nloc <= 0) return;

    for (int i = tid; i < NBT; i += 256) hist[i] = 0;
    __syncthreads();

    for (int k = tid; k < nloc; k += 256) {
        const long i = start + k;
        int b, dlo;
        if (i < E2) {
            int d = ei2[E2 + i]; b = d >> 11; dlo = d & 2047;
        } else {
            int j = (int)(i - E2);
            int d = ei1[E1 + j]; b = NB2 + (d >> 7); dlo = d & 127;
        }
        buck[k] = (unsigned)b | ((unsigned)dlo << 16);
        atomicAdd(&hist[b], 1);
    }
    __syncthreads();

    for (int i = tid; i < NBT; i += 256) {
        const int c = hist[i];
        gbase[i] = (c > 0) ? atomicAdd(&cur[i * CURSTRIDE], c) : 0;
        wloc[i] = 0;
    }
    __syncthreads();

    for (int k = tid; k < nloc; k += 256) {
        const long i = start + k;
        const unsigned bv = buck[k];
        const int b = (int)(bv & 0xffffu), dlo = (int)(bv >> 16);
        int e, s;
        if (i < E2) { e = (int)i; s = ei2[i]; }
        else        { int j = (int)(i - E2); e = j; s = ei1[j]; }
        const int pos = gbase[b] + atomicAdd(&wloc[b], 1);
        if (pos < CAP)
            mid[(size_t)b * CAP + pos] =
                make_uint2((unsigned)e | ((unsigned)dlo << 21), (unsigned)s);
    }
}

// ---------------- LDS scan helper -----------------------------------------

__device__ __forceinline__ void lds_excl_scan(int* cnt, int span, int tid) {
    __shared__ int wpart[4];
    __shared__ int sCarry;
    if (tid == 0) sCarry = 0;
    __syncthreads();
    const int lane = tid & 63, wv = tid >> 6;
    for (int c0 = 0; c0 < span; c0 += 256) {
        const int idx = c0 + tid;
        int v = (idx < span) ? cnt[idx] : 0;
        int inc = v;
        #pragma unroll
        for (int off = 1; off < 64; off <<= 1) {
            int nv = __shfl_up(inc, off, 64);
            if (lane >= off) inc += nv;
        }
        if (lane == 63) wpart[wv] = inc;
        __syncthreads();
        int wpre = 0;
        for (int wq = 0; wq < wv; ++wq) wpre += wpart[wq];
        const int excl = sCarry + wpre + inc - v;
        const int tot = wpart[0] + wpart[1] + wpart[2] + wpart[3];
        __syncthreads();
        if (idx < span) cnt[idx] = excl;
        if (tid == 0) sCarry += tot;
        __syncthreads();
    }
}

// ---------------- csr1: graph-1 buckets -> ord1 (+E2 offset) + rank1 -------
// ord1 record: x = e | (dlo<<21), y = s | (bucket<<20)

__global__ __launch_bounds__(256) void k_csr1(
    const int* __restrict__ cur, const uint2* __restrict__ mid,
    uint2* __restrict__ ord1, int* __restrict__ rank1, int NB2)
{
    __shared__ int cnt[128];
    __shared__ int cnt2[128];
    __shared__ int red[256];

    const int bl = blockIdx.x, tid = threadIdx.x;
    const int bg = NB2 + bl;
    const int fill = min(cur[bg * CURSTRIDE], CAP);

    int part = 0;
    for (int k = NB2 + tid; k < bg; k += 256) part += min(cur[k * CURSTRIDE], CAP);
    red[tid] = part;
    __syncthreads();
    for (int off = 128; off >= 1; off >>= 1) {
        if (tid < off) red[tid] += red[tid + off];
        __syncthreads();
    }
    const int outBase = red[0];  // 0-based within graph-1 order

    if (tid < 128) { cnt[tid] = 0; cnt2[tid] = 0; }
    __syncthreads();
    const size_t mbase = (size_t)bg * CAP;
    for (int i = tid; i < fill; i += 256)
        atomicAdd(&cnt[mid[mbase + i].x >> 21], 1);
    __syncthreads();
    lds_excl_scan(cnt, 128, tid);
    __syncthreads();
    for (int i = tid; i < fill; i += 256) {
        uint2 r = mid[mbase + i];
        const int dl = (int)(r.x >> 21);
        const int rk = atomicAdd(&cnt2[dl], 1);
        const int o = outBase + cnt[dl] + rk;
        ord1[o] = make_uint2(r.x, r.y | ((unsigned)bg << 20));
        rank1[r.x & 0x1FFFFFu] = o;
    }
}

// ---------------- csr2: graph-2 buckets -> ord2 keyed by rank1[d] ----------
// ord2 record: x = e | ((key&0x7FF)<<21), y = s | ((key>>11)<<20)

__global__ __launch_bounds__(256) void k_csr2(
    const int* __restrict__ cur, const uint2* __restrict__ mid,
    uint2* __restrict__ ord2, const int* __restrict__ rank1, int E1)
{
    __shared__ int cnt[2048];
    __shared__ int cnt2[2048];
    __shared__ int red[256];

    const int b = blockIdx.x, tid = threadIdx.x;
    const int node0 = b << 11;
    const int fill = min(cur[b * CURSTRIDE], CAP);

    int part = 0;
    for (int k = tid; k < b; k += 256) part += min(cur[k * CURSTRIDE], CAP);
    red[tid] = part;
    __syncthreads();
    for (int off = 128; off >= 1; off >>= 1) {
        if (tid < off) red[tid] += red[tid + off];
        __syncthreads();
    }
    const int outBase = red[0];

    for (int k = tid; k < 2048; k += 256) { cnt[k] = 0; cnt2[k] = 0; }
    __syncthreads();
    const size_t mbase = (size_t)b * CAP;
    for (int i = tid; i < fill; i += 256)
        atomicAdd(&cnt[mid[mbase + i].x >> 21], 1);
    __syncthreads();
    lds_excl_scan(cnt, 2048, tid);
    __syncthreads();
    for (int i = tid; i < fill; i += 256) {
        uint2 r = mid[mbase + i];
        const int dl = (int)(r.x >> 21);
        const int e  = (int)(r.x & 0x1FFFFFu);
        const int rk = atomicAdd(&cnt2[dl], 1);
        const int o = outBase + cnt[dl] + rk;
        unsigned key = (unsigned)rank1[node0 + dl];
        if (key >= (unsigned)E1) key = 0;  // safety (only hit on CAP overflow)
        ord2[o] = make_uint2((unsigned)e | ((key & 0x7FFu) << 21),
                             r.y | ((key >> 11) << 20));
    }
}

// ---------------- stage 1: MFMA MLP2 + task-parallel reduce -> e_t (bf16) --
// e_t row index = key = rank1[d] (bijective per-d), so segment equality is
// preserved and msg1 can read e_t sequentially at its own ord position.

__global__ __launch_bounds__(256) void k_msg2_agg(
    const float* __restrict__ x2f, const uint4* __restrict__ x2b,
    const float* __restrict__ ea2, const uint4* __restrict__ ea2b,
    const uint2* __restrict__ ord, const unsigned char* __restrict__ wimg,
    unsigned int* __restrict__ e_t, int E, int use_bf16, int use_ea2b)
{
    __shared__ __align__(16) unsigned char sBuf[32768];
    unsigned short* smsg = (unsigned short*)sBuf;                       // 16896 B
    int* sdst = (int*)(sBuf + 16896);                                   // [258]
    int* rstart = (int*)(sBuf + 16896 + 1032);                          // [257]
    unsigned long long* wmaskS = (unsigned long long*)(sBuf + 16896 + 1032 + 1032);

    const int tid = threadIdx.x;
    const int base = blockIdx.x * 256, p = base + tid;

    int e = 0, s = 0, d = -1, dp_ = -1, dn_ = -1;
    if (p < E) {
        uint2 o = ord[p];
        e = (int)(o.x & 0x1FFFFFu); s = (int)(o.y & 0xFFFFFu);
        d = (int)((o.x >> 21) | ((o.y >> 20) << 11));   // key
    }
    if (tid == 0) {
        if (base > 0) { uint2 o = ord[base - 1]; dp_ = (int)((o.x >> 21) | ((o.y >> 20) << 11)); }
        if (base + 256 < E) { uint2 o = ord[base + 256]; dn_ = (int)((o.x >> 21) | ((o.y >> 20) << 11)); }
    }

    // stage input row: [x2[s](32ch), ea2[e](16ch), 0(16ch)] as bf16, swizzled
    {
        uint4 ch[8];
        if (use_bf16) {
            const uint4* xr = x2b + (size_t)s * 4;
            #pragma unroll
            for (int c = 0; c < 4; ++c) ch[c] = xr[c];
        } else {
            const float4* xs = (const float4*)(x2f + (size_t)s * 32);
            #pragma unroll
            for (int c = 0; c < 4; ++c) {
                float4 a = xs[2 * c], b = xs[2 * c + 1];
                ch[c].x = pack2(a.x, a.y); ch[c].y = pack2(a.z, a.w);
                ch[c].z = pack2(b.x, b.y); ch[c].w = pack2(b.z, b.w);
            }
        }
        if (use_ea2b) {
            ch[4] = ea2b[(size_t)e * 2];
            ch[5] = ea2b[(size_t)e * 2 + 1];
        } else {
            const float4* es = (const float4*)(ea2 + (size_t)e * 16);
            #pragma unroll
            for (int c = 0; c < 2; ++c) {
                float4 a = es[2 * c], b = es[2 * c + 1];
                ch[4 + c].x = pack2(a.x, a.y); ch[4 + c].y = pack2(a.z, a.w);
                ch[4 + c].z = pack2(b.x, b.y); ch[4 + c].w = pack2(b.z, b.w);
            }
        }
        ch[6] = make_uint4(0, 0, 0, 0);
        ch[7] = make_uint4(0, 0, 0, 0);
        #pragma unroll
        for (int c = 0; c < 8; ++c)
            *(uint4*)(sBuf + swz(tid, c * 16)) = ch[c];
    }
    __syncthreads();  // S1

    const int lane = tid & 63, wv = tid >> 6;
    const int lr = lane & 15, lk = lane >> 4;
    const int band = wv * 64;
    const unsigned char* gWa = wimg;
    const unsigned char* gWb = wimg + 8192;
    const float* gba = (const float*)(wimg + 12288);
    const float* gbb = (const float*)(wimg + 12544);

    // ---- layer A: H = relu(In @ Wa + ba) ----
    f32x4 accA[4][4];
    #pragma unroll
    for (int n = 0; n < 4; ++n) {
        float bv = gba[n * 16 + lr];
        #pragma unroll
        for (int m = 0; m < 4; ++m) accA[m][n] = (f32x4){bv, bv, bv, bv};
    }
    #pragma unroll
    for (int ks = 0; ks < 2; ++ks) {
        const int kb = ks * 64 + lk * 16;
        bf16x8 af[4], bfr[4];
        #pragma unroll
        for (int m = 0; m < 4; ++m)
            af[m] = *(const bf16x8*)(sBuf + swz(band + m * 16 + lr, kb));
        #pragma unroll
        for (int n = 0; n < 4; ++n) {
            int rw = n * 16 + lr;
            bfr[n] = *(const bf16x8*)(gWa + rw * 128 + (kb ^ ((rw & 7) << 4)));
        }
        #pragma unroll
        for (int m = 0; m < 4; ++m)
            #pragma unroll
            for (int n = 0; n < 4; ++n)
                accA[m][n] = __builtin_amdgcn_mfma_f32_16x16x32_bf16(af[m], bfr[n], accA[m][n], 0, 0, 0);
    }
    #pragma unroll
    for (int m = 0; m < 4; ++m)
        #pragma unroll
        for (int n = 0; n < 4; ++n)
            #pragma unroll
            for (int rr = 0; rr < 4; ++rr) {
                int grow = band + m * 16 + lk * 4 + rr;
                int cb = 2 * (n * 16 + lr);
                *(unsigned short*)(sBuf + swz(grow, cb)) = f2bf(fmaxf(accA[m][n][rr], 0.0f));
            }

    // ---- layer B: Out = H @ Wb + bb ----
    f32x4 accB[4][2];
    #pragma unroll
    for (int n = 0; n < 2; ++n) {
        float bv = gbb[n * 16 + lr];
        #pragma unroll
        for (int m = 0; m < 4; ++m) accB[m][n] = (f32x4){bv, bv, bv, bv};
    }
    #pragma unroll
    for (int ks = 0; ks < 2; ++ks) {
        const int kb = ks * 64 + lk * 16;
        bf16x8 af[4], bfr[2];
        #pragma unroll
        for (int m = 0; m < 4; ++m)
            af[m] = *(const bf16x8*)(sBuf + swz(band + m * 16 + lr, kb));
        #pragma unroll
        for (int n = 0; n < 2; ++n) {
            int rw = n * 16 + lr;
            bfr[n] = *(const bf16x8*)(gWb + rw * 128 + (kb ^ ((rw & 7) << 4)));
        }
        #pragma unroll
        for (int m = 0; m < 4; ++m)
            #pragma unroll
            for (int n = 0; n < 2; ++n)
                accB[m][n] = __builtin_amdgcn_mfma_f32_16x16x32_bf16(af[m], bfr[n], accB[m][n], 0, 0, 0);
    }
    __syncthreads();  // S3

    #pragma unroll
    for (int m = 0; m < 4; ++m)
        #pragma unroll
        for (int n = 0; n < 2; ++n)
            #pragma unroll
            for (int rr = 0; rr < 4; ++rr)
                smsg[(band + m * 16 + lk * 4 + rr) * 33 + n * 16 + lr] = f2bf(accB[m][n][rr]);
    sdst[tid] = d;
    if (tid == 0) { sdst[256] = dn_; sdst[257] = dp_; }
    __syncthreads();  // S4a

    const bool leader = (p < E) && (tid == 0 || sdst[tid - 1] != d);
    wmaskS[wv] = __ballot(leader);
    __syncthreads();  // S4b

    int nruns = __popcll(wmaskS[0]) + __popcll(wmaskS[1]) + __popcll(wmaskS[2]) + __popcll(wmaskS[3]);
    if (leader) {
        int before = __popcll(wmaskS[wv] & ((1ULL << lane) - 1));
        for (int w = 0; w < wv; ++w) before += __popcll(wmaskS[w]);
        rstart[before] = tid;
    }
    const int vcnt = (E - base < 256) ? (E - base) : 256;
    if (tid == 0) rstart[nruns] = vcnt;
    __syncthreads();  // S5

    const int sPrev = sdst[257];
    const int ntask = nruns * 32;
    for (int task = tid; task < ntask; task += 256) {
        const int run = task >> 5, c = task & 31;
        const int rs = rstart[run], re = rstart[run + 1];
        const int dd = sdst[rs];
        float acc = 0.0f;
        for (int qq = rs; qq < re; ++qq) acc += bf2f(smsg[qq * 33 + c]);
        const bool gs = (rs > 0) || (base == 0) || (sPrev != dd);
        const bool ge = (re < 256) || (sdst[256] != dd);
        if (gs && ge) {
            ((unsigned short*)e_t)[(size_t)dd * 32 + c] = f2bf(acc);
        } else {
            unsigned int* a32 = e_t + (size_t)dd * 16 + (c >> 1);
            const int sh = (c & 1) * 16;
            unsigned int old = *a32;
            while (true) {
                float cur2 = bf2f((old >> sh) & 0xffffu);
                unsigned int nb = f2bf(cur2 + acc);
                unsigned int nv = (old & ~(0xffffu << sh)) | (nb << sh);
                unsigned int prev = atomicCAS(a32, old, nv);
                if (prev == old) break;
                old = prev;
            }
        }
    }
}

// ---------------- stage 2: MFMA MLP1 + task-parallel reduce -> h (f32) -----
// e_t row for record at position p is exactly p (rank-ordered) -> coalesced.

__global__ __launch_bounds__(256) void k_msg1_agg(
    const float* __restrict__ x1f, const uint4* __restrict__ x1b,
    const unsigned int* __restrict__ e_t,
    const uint2* __restrict__ ord, const unsigned char* __restrict__ wimg,
    float* __restrict__ h, int E, int NB2, int use_bf16)
{
    __shared__ __align__(16) unsigned char sBuf[32768];
    unsigned short* smsg = (unsigned short*)sBuf;
    int* sdst = (int*)(sBuf + 16896);
    int* rstart = (int*)(sBuf + 16896 + 1032);
    unsigned long long* wmaskS = (unsigned long long*)(sBuf + 16896 + 1032 + 1032);

    const int tid = threadIdx.x;
    const int base = blockIdx.x * 256, p = base + tid;

    int s = 0, d = -1, dp_ = -1, dn_ = -1;
    if (p < E) {
        uint2 o = ord[p];
        s = (int)(o.y & 0xFFFFFu);
        d = (((int)(o.y >> 20) - NB2) << 7) + (int)(o.x >> 21);
    }
    if (tid == 0) {
        if (base > 0) { uint2 o = ord[base - 1]; dp_ = (((int)(o.y >> 20) - NB2) << 7) + (int)(o.x >> 21); }
        if (base + 256 < E) { uint2 o = ord[base + 256]; dn_ = (((int)(o.y >> 20) - NB2) << 7) + (int)(o.x >> 21); }
    }

    // stage input row: [x1[s](32ch), e_t[p](32ch bf16, SEQUENTIAL)]
    {
        uint4 ch[8];
        if (use_bf16) {
            const uint4* xr = x1b + (size_t)s * 4;
            #pragma unroll
            for (int c = 0; c < 4; ++c) ch[c] = xr[c];
        } else {
            const float4* xs = (const float4*)(x1f + (size_t)s * 32);
            #pragma unroll
            for (int c = 0; c < 4; ++c) {
                float4 a = xs[2 * c], b = xs[2 * c + 1];
                ch[c].x = pack2(a.x, a.y); ch[c].y = pack2(a.z, a.w);
                ch[c].z = pack2(b.x, b.y); ch[c].w = pack2(b.z, b.w);
            }
        }
        const int erow = (p < E) ? p : (E - 1);
        const uint4* er = (const uint4*)(e_t + (size_t)erow * 16);
        #pragma unroll
        for (int c = 0; c < 4; ++c) ch[4 + c] = er[c];
        #pragma unroll
        for (int c = 0; c < 8; ++c)
            *(uint4*)(sBuf + swz(tid, c * 16)) = ch[c];
    }
    __syncthreads();  // S1

    const int lane = tid & 63, wv = tid >> 6;
    const int lr = lane & 15, lk = lane >> 4;
    const int band = wv * 64;
    const unsigned char* gWa = wimg;
    const unsigned char* gWb = wimg + 8192;
    const float* gba = (const float*)(wimg + 12288);
    const float* gbb = (const float*)(wimg + 12544);

    f32x4 accA[4][4];
    #pragma unroll
    for (int n = 0; n < 4; ++n) {
        float bv = gba[n * 16 + lr];
        #pragma unroll
        for (int m = 0; m < 4; ++m) accA[m][n] = (f32x4){bv, bv, bv, bv};
    }
    #pragma unroll
    for (int ks = 0; ks < 2; ++ks) {
        const int kb = ks * 64 + lk * 16;
        bf16x8 af[4], bfr[4];
        #pragma unroll
        for (int m = 0; m < 4; ++m)
            af[m] = *(const bf16x8*)(sBuf + swz(band + m * 16 + lr, kb));
        #pragma unroll
        for (int n = 0; n < 4; ++n) {
            int rw = n * 16 + lr;
            bfr[n] = *(const bf16x8*)(gWa + rw * 128 + (kb ^ ((rw & 7) << 4)));
        }
        #pragma unroll
        for (int m = 0; m < 4; ++m)
            #pragma unroll
            for (int n = 0; n < 4; ++n)
                accA[m][n] = __builtin_amdgcn_mfma_f32_16x16x32_bf16(af[m], bfr[n], accA[m][n], 0, 0, 0);
    }
    #pragma unroll
    for (int m = 0; m < 4; ++m)
        #pragma unroll
        for (int n = 0; n < 4; ++n)
            #pragma unroll
            for (int rr = 0; rr < 4; ++rr) {
                int grow = band + m * 16 + lk * 4 + rr;
                int cb = 2 * (n * 16 + lr);
                *(unsigned short*)(sBuf + swz(grow, cb)) = f2bf(fmaxf(accA[m][n][rr], 0.0f));
            }

    f32x4 accB[4][2];
    #pragma unroll
    for (int n = 0; n < 2; ++n) {
        float bv = gbb[n * 16 + lr];
        #pragma unroll
        for (int m = 0; m < 4; ++m) accB[m][n] = (f32x4){bv, bv, bv, bv};
    }
    #pragma unroll
    for (int ks = 0; ks < 2; ++ks) {
        const int kb = ks * 64 + lk * 16;
        bf16x8 af[4], bfr[2];
        #pragma unroll
        for (int m = 0; m < 4; ++m)
            af[m] = *(const bf16x8*)(sBuf + swz(band + m * 16 + lr, kb));
        #pragma unroll
        for (int n = 0; n < 2; ++n) {
            int rw = n * 16 + lr;
            bfr[n] = *(const bf16x8*)(gWb + rw * 128 + (kb ^ ((rw & 7) << 4)));
        }
        #pragma unroll
        for (int m = 0; m < 4; ++m)
            #pragma unroll
            for (int n = 0; n < 2; ++n)
                accB[m][n] = __builtin_amdgcn_mfma_f32_16x16x32_bf16(af[m], bfr[n], accB[m][n], 0, 0, 0);
    }
    __syncthreads();  // S3

    #pragma unroll
    for (int m = 0; m < 4; ++m)
        #pragma unroll
        for (int n = 0; n < 2; ++n)
            #pragma unroll
            for (int rr = 0; rr < 4; ++rr)
                smsg[(band + m * 16 + lk * 4 + rr) * 33 + n * 16 + lr] = f2bf(accB[m][n][rr]);
    sdst[tid] = d;
    if (tid == 0) { sdst[256] = dn_; sdst[257] = dp_; }
    __syncthreads();  // S4a

    const bool leader = (p < E) && (tid == 0 || sdst[tid - 1] != d);
    wmaskS[wv] = __ballot(leader);
    __syncthreads();  // S4b

    int nruns = __popcll(wmaskS[0]) + __popcll(wmaskS[1]) + __popcll(wmaskS[2]) + __popcll(wmaskS[3]);
    if (leader) {
        int before = __popcll(wmaskS[wv] & ((1ULL << lane) - 1));
        for (int w = 0; w < wv; ++w) before += __popcll(wmaskS[w]);
        rstart[before] = tid;
    }
    const int vcnt = (E - base < 256) ? (E - base) : 256;
    if (tid == 0) rstart[nruns] = vcnt;
    __syncthreads();  // S5

    const int sPrev = sdst[257];
    const int ntask = nruns * 32;
    for (int task = tid; task < ntask; task += 256) {
        const int run = task >> 5, c = task & 31;
        const int rs = rstart[run], re = rstart[run + 1];
        const int dd = sdst[rs];
        float acc = 0.0f;
        for (int qq = rs; qq < re; ++qq) acc += bf2f(smsg[qq * 33 + c]);
        const bool gs = (rs > 0) || (base == 0) || (sPrev != dd);
        const bool ge = (re < 256) || (sdst[256] != dd);
        if (gs && ge) h[(size_t)dd * 32 + c] = acc;
        else atomicAdd(h + (size_t)dd * 32 + c, acc);
    }
}

// ---------------- stage 3: pool per graph (batch is sorted) ----------------

__device__ __forceinline__ int lower_bound_i(const int* a, int n, int key) {
    int lo = 0, hi = n;
    while (lo < hi) {
        int mid = (lo + hi) >> 1;
        if (a[mid] < key) lo = mid + 1; else hi = mid;
    }
    return lo;
}

__global__ __launch_bounds__(256) void k_pool(const float* __restrict__ h,
                                              const int* __restrict__ batch,
                                              float* __restrict__ out, int N1) {
    const int g = blockIdx.x;
    const int lo = lower_bound_i(batch, N1, g);
    const int hi = lower_bound_i(batch, N1, g + 1);
    const int tid = threadIdx.x;
    const int c = tid & 31, rg = tid >> 5;
    float acc = 0.0f;
    for (int n = lo + rg; n < hi; n += 8) acc += h[(size_t)n * 32 + c];
    __shared__ float red[256];
    red[tid] = acc;
    __syncthreads();
    for (int off = 128; off >= 32; off >>= 1) {
        if (tid < off) red[tid] += red[tid + off];
        __syncthreads();
    }
    if (tid < 32) out[g * 32 + tid] = red[tid] * 0.5f;
}

// ---------------------------------------------------------------------------

extern "C" void kernel_launch(void* const* d_in, const int* in_sizes, int n_in,
                              void* d_out, int out_size, void* d_ws, size_t ws_size,
                              hipStream_t stream) {
    const float* x1  = (const float*)d_in[0];
    const float* x2  = (const float*)d_in[1];
    const int*   ei1 = (const int*)d_in[2];
    const int*   ei2 = (const int*)d_in[3];
    const int*   xb  = (const int*)d_in[4];
    const float* ea2 = (const float*)d_in[5];
    const float* W2a = (const float*)d_in[6];
    const float* b2a = (const float*)d_in[7];
    const float* W2b = (const float*)d_in[8];
    const float* b2b = (const float*)d_in[9];
    const float* W1a = (const float*)d_in[10];
    const float* b1a = (const float*)d_in[11];
    const float* W1b = (const float*)d_in[12];
    const float* b1b = (const float*)d_in[13];

    const int N1 = in_sizes[0] / 32;   // 20000
    const int E1 = in_sizes[2] / 2;    // 640000
    const int E2 = in_sizes[3] / 2;    // 1280000
    const int N2 = in_sizes[1] / 32;   // 640000 (== E1)
    const int Etot = E2 + E1;

    const int NB2 = (N2 + 2047) >> 11;  // 313
    const int NB1 = (N1 + 127) >> 7;    // 157
    const int NBT = NB2 + NB1;          // 470

    const size_t sz_wpack = 25600;
    const size_t sz_cur   = (size_t)NBT * CURSTRIDE * 4;
    const size_t sz_et    = (size_t)N2 * 64;
    const size_t sz_h     = (size_t)N1 * 128;
    const size_t sz_ord   = (size_t)Etot * 8;
    const size_t sz_mid   = (size_t)NBT * CAP * 8;               // 17.3 MB
    const size_t sz_rank  = (size_t)N2 * 4;                      // 2.56 MB
    // rank1 lives in regionA after mid (regA >= et+h = 43.6 MB > mid+rank)
    const size_t regA     = ((sz_mid + sz_rank) > sz_et + sz_h) ? (sz_mid + sz_rank)
                                                                : (sz_et + sz_h);
    const size_t sz_x2b   = (size_t)N2 * 64;
    const size_t sz_x1b   = (size_t)N1 * 64;
    const size_t sz_ea2b  = (size_t)E2 * 32;
    const size_t need_x   = sz_ord + regA + sz_x2b + sz_x1b + sz_wpack + sz_cur;
    const size_t need_xe  = need_x + sz_ea2b;

    const int use_bf16 = (ws_size >= need_x) ? 1 : 0;
    const int use_ea2b = (ws_size >= need_xe) ? 1 : 0;

    char* w = (char*)d_ws;
    uint2* ord = (uint2*)w;            w += sz_ord;
    char* regionA = w;                 w += regA;
    uint4* x2b = (uint4*)w;            if (use_bf16) w += sz_x2b;
    uint4* x1b = (uint4*)w;            if (use_bf16) w += sz_x1b;
    uint4* ea2b = (uint4*)w;           if (use_ea2b) w += sz_ea2b;
    unsigned char* wpack = (unsigned char*)w;  w += sz_wpack;
    int* cur = (int*)w;

    unsigned int* e_t = (unsigned int*)regionA;
    float* h = (float*)(regionA + sz_et);
    uint2* mid = (uint2*)regionA;
    int* rank1 = (int*)(regionA + sz_mid);   // dead after csr2; wiped by memset

    const int NBB = (Etot + EPB - 1) / EPB;
    const long xn2 = use_bf16 ? (long)N2 * 4 : 0;
    const long xn1 = use_bf16 ? (long)N1 * 4 : 0;
    const long xne = use_ea2b ? (long)E2 * 2 : 0;

    // 1) weights + zero cursors
    k_prep0<<<2, 256, 0, stream>>>(W2a, b2a, W2b, b2b, W1a, b1a, W1b, b1b,
                                   wpack, cur, NBT * CURSTRIDE);
    // 2) fused bucket-scatter + bf16 table cvt
    k_bscat_cvt<<<NBB + NCVT, 256, 0, stream>>>(
        ei2, E2, ei1, E1, cur, mid, NB2, NBT, Etot, NBB,
        x2, x2b, x1, x1b, ea2, ea2b, xn2, xn1, xne);
    // 3) csr1 (graph-1: ord1 + rank1), then csr2 (graph-2: keyed by rank1[d])
    k_csr1<<<NB1, 256, 0, stream>>>(cur, mid, ord + E2, rank1, NB2);
    k_csr2<<<NB2, 256, 0, stream>>>(cur, mid, ord, rank1, E1);
    // 4) zero e_t + h (overwrites mid + rank1; both dead)
    hipMemsetAsync(regionA, 0, sz_et + sz_h, stream);
    // 5) stage 1 (e_t rows at rank keys)
    k_msg2_agg<<<(E2 + 255) / 256, 256, 0, stream>>>(
        x2, x2b, ea2, ea2b, ord, wpack, e_t, E2, use_bf16, use_ea2b);
    // 6) stage 2 (e_t read sequentially at own position)
    k_msg1_agg<<<(E1 + 255) / 256, 256, 0, stream>>>(
        x1, x1b, e_t, ord + E2, wpack + 12672, h, E1, NB2, use_bf16);
    // 7) pool
    k_pool<<<NUM_GRAPHS, 256, 0, stream>>>(h, xb, (float*)d_out, N1);
}

// Round 14
// 253.776 us; speedup vs baseline: 1.0970x; 1.0970x over previous
//
#include <hip/hip_runtime.h>
#include <hip/hip_bf16.h>

// ---------------------------------------------------------------------------
// MOF_Net: DGCN(graph2) -> e_t ; MOLGCN(graph1) -> h ; global add pool /2
// N1=20000, E1=640000, N2=640000(==E1), E2=1280000
// Round 14: R12 pipeline; ea2b table dropped (random 32B row fetches the
// same 64B sector as f32 -- table saved nothing; its cvt cost was real).
// ---------------------------------------------------------------------------

#define NUM_GRAPHS 64
#define CAP 4608        // per-bucket capacity (mean ~4090, +8 sigma)
#define CURSTRIDE 16    // ints per cursor (64B line padding)
#define EPB 8192        // edges per bscat block
#define NCVT 1024       // cvt role blocks in fused kernel

typedef __attribute__((ext_vector_type(8))) short bf16x8;
typedef __attribute__((ext_vector_type(4))) float f32x4;

__device__ __forceinline__ unsigned short f2bf(float x) {
    __hip_bfloat16 b = __float2bfloat16(x);
    return *(unsigned short*)&b;
}
__device__ __forceinline__ float bf2f(unsigned int u16) {
    unsigned short us = (unsigned short)u16;
    __hip_bfloat16 b = *(__hip_bfloat16*)&us;
    return __bfloat162float(b);
}
__device__ __forceinline__ unsigned int pack2(float lo, float hi) {
    return (unsigned int)f2bf(lo) | ((unsigned int)f2bf(hi) << 16);
}
__device__ __forceinline__ uint4 cvt8(const float* src) {
    const float4* s4 = (const float4*)src;
    float4 a = s4[0], b = s4[1];
    return make_uint4(pack2(a.x, a.y), pack2(a.z, a.w),
                      pack2(b.x, b.y), pack2(b.z, b.w));
}
__device__ __forceinline__ int swz(int row, int kb) {
    return row * 128 + (kb ^ ((row & 7) << 4));
}

// ---------------- prep0: pack weight images + zero bucket cursors ----------

__global__ __launch_bounds__(256) void k_prep0(
    const float* __restrict__ W2a, const float* __restrict__ b2a,
    const float* __restrict__ W2b, const float* __restrict__ b2b,
    const float* __restrict__ W1a, const float* __restrict__ b1a,
    const float* __restrict__ W1b, const float* __restrict__ b1b,
    unsigned char* __restrict__ wpack, int* __restrict__ cur, int ncur)
{
    const int tid = threadIdx.x;
    if (blockIdx.x == 0) {
        unsigned char* img1 = wpack;
        unsigned char* img2 = wpack + 12672;
        for (int i = tid; i < 64 * 64; i += 256) {
            int n = i >> 6, k = i & 63;
            float v1 = (k < 48) ? W2a[k * 64 + n] : 0.0f;
            *(unsigned short*)(img1 + n * 128 + ((2 * k) ^ ((n & 7) << 4))) = f2bf(v1);
            *(unsigned short*)(img2 + n * 128 + ((2 * k) ^ ((n & 7) << 4))) = f2bf(W1a[k * 64 + n]);
        }
        for (int i = tid; i < 32 * 64; i += 256) {
            int n = i >> 6, k = i & 63;
            *(unsigned short*)(img1 + 8192 + n * 128 + ((2 * k) ^ ((n & 7) << 4))) = f2bf(W2b[k * 32 + n]);
            *(unsigned short*)(img2 + 8192 + n * 128 + ((2 * k) ^ ((n & 7) << 4))) = f2bf(W1b[k * 32 + n]);
        }
        if (tid < 64) {
            ((float*)(img1 + 12288))[tid] = b2a[tid];
            ((float*)(img2 + 12288))[tid] = b1a[tid];
        }
        if (tid < 32) {
            ((float*)(img1 + 12544))[tid] = b2b[tid];
            ((float*)(img2 + 12544))[tid] = b1b[tid];
        }
    } else {
        for (int i = tid; i < ncur; i += 256) cur[i] = 0;
    }
}

// ---------------- fused: bucket scatter (block-claimed runs) + cvt ---------
// mid record: x = e | (dlo<<21), y = s

__global__ __launch_bounds__(256) void k_bscat_cvt(
    const int* __restrict__ ei2, int E2, const int* __restrict__ ei1, int E1,
    int* __restrict__ cur, uint2* __restrict__ mid, int NB2, int NBT, int Etot, int NBB,
    const float* __restrict__ x2, uint4* __restrict__ x2b,
    const float* __restrict__ x1, uint4* __restrict__ x1b,
    long xn2, long xn1)
{
    __shared__ unsigned int buck[EPB];   // b | dlo<<16
    __shared__ int hist[512];
    __shared__ int gbase[512];
    __shared__ int wloc[512];

    const int tid = threadIdx.x;
    if (blockIdx.x >= NBB) {
        const long tot = xn2 + xn1;
        const long stride = (long)NCVT * 256;
        for (long i = (long)(blockIdx.x - NBB) * 256 + tid; i < tot; i += stride) {
            if (i < xn2) x2b[i] = cvt8(x2 + i * 8);
            else { long j = i - xn2; x1b[j] = cvt8(x1 + j * 8); }
        }
        return;
    }

    const long start = (long)blockIdx.x * EPB;
    const int nloc = (int)(((long)Etot - start) < EPB ? ((long)Etot - start) : EPB);
    if (nloc <= 0) return;

    for (int i = tid; i < NBT; i += 256) hist[i] = 0;
    __syncthreads();

    for (int k = tid; k < nloc; k += 256) {
        const long i = start + k;
        int b, dlo;
        if (i < E2) {
            int d = ei2[E2 + i]; b = d >> 11; dlo = d & 2047;
        } else {
            int j = (int)(i - E2);
            int d = ei1[E1 + j]; b = NB2 + (d >> 7); dlo = d & 127;
        }
        buck[k] = (unsigned)b | ((unsigned)dlo << 16);
        atomicAdd(&hist[b], 1);
    }
    __syncthreads();

    for (int i = tid; i < NBT; i += 256) {
        const int c = hist[i];
        gbase[i] = (c > 0) ? atomicAdd(&cur[i * CURSTRIDE], c) : 0;
        wloc[i] = 0;
    }
    __syncthreads();

    for (int k = tid; k < nloc; k += 256) {
        const long i = start + k;
        const unsigned bv = buck[k];
        const int b = (int)(bv & 0xffffu), dlo = (int)(bv >> 16);
        int e, s;
        if (i < E2) { e = (int)i; s = ei2[i]; }
        else        { int j = (int)(i - E2); e = j; s = ei1[j]; }
        const int pos = gbase[b] + atomicAdd(&wloc[b], 1);
        if (pos < CAP)
            mid[(size_t)b * CAP + pos] =
                make_uint2((unsigned)e | ((unsigned)dlo << 21), (unsigned)s);
    }
}

// ---------------- per-bucket CSR finalize: node-sorted 8B ord records ------
// ord record: x = e | (dlo<<21), y = s | (bucket<<20)

__global__ __launch_bounds__(256) void k_csr(
    const int* __restrict__ cur, const uint2* __restrict__ mid,
    uint2* __restrict__ ord, int NB2, int E2)
{
    __shared__ int cnt[2048];
    __shared__ int cnt2[2048];
    __shared__ int red[256];
    __shared__ int wpart[4];
    __shared__ int sCarry;

    const int b = blockIdx.x, tid = threadIdx.x;
    const bool g2 = (b < NB2);
    const int span = g2 ? 2048 : 128;
    const int lo = g2 ? 0 : NB2;
    const int fill = min(cur[b * CURSTRIDE], CAP);

    int part = 0;
    for (int k = lo + tid; k < b; k += 256) part += min(cur[k * CURSTRIDE], CAP);
    red[tid] = part;
    __syncthreads();
    for (int off = 128; off >= 1; off >>= 1) {
        if (tid < off) red[tid] += red[tid + off];
        __syncthreads();
    }
    const int outBase = (g2 ? 0 : E2) + red[0];

    for (int k = tid; k < span; k += 256) cnt[k] = 0;
    __syncthreads();

    const size_t mbase = (size_t)b * CAP;
    for (int i = tid; i < fill; i += 256)
        atomicAdd(&cnt[mid[mbase + i].x >> 21], 1);
    __syncthreads();

    if (tid == 0) sCarry = 0;
    __syncthreads();
    const int lane = tid & 63, wv = tid >> 6;
    for (int c0 = 0; c0 < span; c0 += 256) {
        const int idx = c0 + tid;
        int v = (idx < span) ? cnt[idx] : 0;
        int inc = v;
        #pragma unroll
        for (int off = 1; off < 64; off <<= 1) {
            int nv = __shfl_up(inc, off, 64);
            if (lane >= off) inc += nv;
        }
        if (lane == 63) wpart[wv] = inc;
        __syncthreads();
        int wpre = 0;
        for (int wq = 0; wq < wv; ++wq) wpre += wpart[wq];
        const int excl = sCarry + wpre + inc - v;
        const int tot = wpart[0] + wpart[1] + wpart[2] + wpart[3];
        __syncthreads();
        if (idx < span) cnt[idx] = excl;
        if (tid == 0) sCarry += tot;
        __syncthreads();
    }

    for (int k = tid; k < span; k += 256) cnt2[k] = 0;
    __syncthreads();

    for (int i = tid; i < fill; i += 256) {
        uint2 r = mid[mbase + i];
        const int dl = (int)(r.x >> 21);
        const int rk = atomicAdd(&cnt2[dl], 1);
        ord[outBase + cnt[dl] + rk] = make_uint2(r.x, r.y | ((unsigned)b << 20));
    }
}

// ---------------- stage 1: MFMA MLP2 + task-parallel reduce -> e_t (bf16) --

__global__ __launch_bounds__(256) void k_msg2_agg(
    const float* __restrict__ x2f, const uint4* __restrict__ x2b,
    const float* __restrict__ ea2,
    const uint2* __restrict__ ord, const unsigned char* __restrict__ wimg,
    unsigned int* __restrict__ e_t, int E, int use_bf16)
{
    __shared__ __align__(16) unsigned char sBuf[32768];
    unsigned short* smsg = (unsigned short*)sBuf;                       // 16896 B
    int* sdst = (int*)(sBuf + 16896);                                   // [258]
    int* rstart = (int*)(sBuf + 16896 + 1032);                          // [257]
    unsigned long long* wmaskS = (unsigned long long*)(sBuf + 16896 + 1032 + 1032);

    const int tid = threadIdx.x;
    const int base = blockIdx.x * 256, p = base + tid;

    int e = 0, s = 0, d = -1, dp_ = -1, dn_ = -1;
    if (p < E) {
        uint2 o = ord[p];
        e = (int)(o.x & 0x1FFFFFu); s = (int)(o.y & 0xFFFFFu);
        d = ((int)(o.y >> 20) << 11) + (int)(o.x >> 21);
    }
    if (tid == 0) {
        if (base > 0) { uint2 o = ord[base - 1]; dp_ = ((int)(o.y >> 20) << 11) + (int)(o.x >> 21); }
        if (base + 256 < E) { uint2 o = ord[base + 256]; dn_ = ((int)(o.y >> 20) << 11) + (int)(o.x >> 21); }
    }

    // stage input row: [x2[s](32ch), ea2[e](16ch f32->bf16), 0(16ch)]
    {
        uint4 ch[8];
        if (use_bf16) {
            const uint4* xr = x2b + (size_t)s * 4;
            #pragma unroll
            for (int c = 0; c < 4; ++c) ch[c] = xr[c];
        } else {
            const float4* xs = (const float4*)(x2f + (size_t)s * 32);
            #pragma unroll
            for (int c = 0; c < 4; ++c) {
                float4 a = xs[2 * c], b = xs[2 * c + 1];
                ch[c].x = pack2(a.x, a.y); ch[c].y = pack2(a.z, a.w);
                ch[c].z = pack2(b.x, b.y); ch[c].w = pack2(b.z, b.w);
            }
        }
        {
            const float4* es = (const float4*)(ea2 + (size_t)e * 16);
            #pragma unroll
            for (int c = 0; c < 2; ++c) {
                float4 a = es[2 * c], b = es[2 * c + 1];
                ch[4 + c].x = pack2(a.x, a.y); ch[4 + c].y = pack2(a.z, a.w);
                ch[4 + c].z = pack2(b.x, b.y); ch[4 + c].w = pack2(b.z, b.w);
            }
        }
        ch[6] = make_uint4(0, 0, 0, 0);
        ch[7] = make_uint4(0, 0, 0, 0);
        #pragma unroll
        for (int c = 0; c < 8; ++c)
            *(uint4*)(sBuf + swz(tid, c * 16)) = ch[c];
    }
    __syncthreads();  // S1

    const int lane = tid & 63, wv = tid >> 6;
    const int lr = lane & 15, lk = lane >> 4;
    const int band = wv * 64;
    const unsigned char* gWa = wimg;
    const unsigned char* gWb = wimg + 8192;
    const float* gba = (const float*)(wimg + 12288);
    const float* gbb = (const float*)(wimg + 12544);

    // ---- layer A: H = relu(In @ Wa + ba) ----
    f32x4 accA[4][4];
    #pragma unroll
    for (int n = 0; n < 4; ++n) {
        float bv = gba[n * 16 + lr];
        #pragma unroll
        for (int m = 0; m < 4; ++m) accA[m][n] = (f32x4){bv, bv, bv, bv};
    }
    #pragma unroll
    for (int ks = 0; ks < 2; ++ks) {
        const int kb = ks * 64 + lk * 16;
        bf16x8 af[4], bfr[4];
        #pragma unroll
        for (int m = 0; m < 4; ++m)
            af[m] = *(const bf16x8*)(sBuf + swz(band + m * 16 + lr, kb));
        #pragma unroll
        for (int n = 0; n < 4; ++n) {
            int rw = n * 16 + lr;
            bfr[n] = *(const bf16x8*)(gWa + rw * 128 + (kb ^ ((rw & 7) << 4)));
        }
        #pragma unroll
        for (int m = 0; m < 4; ++m)
            #pragma unroll
            for (int n = 0; n < 4; ++n)
                accA[m][n] = __builtin_amdgcn_mfma_f32_16x16x32_bf16(af[m], bfr[n], accA[m][n], 0, 0, 0);
    }
    #pragma unroll
    for (int m = 0; m < 4; ++m)
        #pragma unroll
        for (int n = 0; n < 4; ++n)
            #pragma unroll
            for (int rr = 0; rr < 4; ++rr) {
                int grow = band + m * 16 + lk * 4 + rr;
                int cb = 2 * (n * 16 + lr);
                *(unsigned short*)(sBuf + swz(grow, cb)) = f2bf(fmaxf(accA[m][n][rr], 0.0f));
            }

    // ---- layer B: Out = H @ Wb + bb ----
    f32x4 accB[4][2];
    #pragma unroll
    for (int n = 0; n < 2; ++n) {
        float bv = gbb[n * 16 + lr];
        #pragma unroll
        for (int m = 0; m < 4; ++m) accB[m][n] = (f32x4){bv, bv, bv, bv};
    }
    #pragma unroll
    for (int ks = 0; ks < 2; ++ks) {
        const int kb = ks * 64 + lk * 16;
        bf16x8 af[4], bfr[2];
        #pragma unroll
        for (int m = 0; m < 4; ++m)
            af[m] = *(const bf16x8*)(sBuf + swz(band + m * 16 + lr, kb));
        #pragma unroll
        for (int n = 0; n < 2; ++n) {
            int rw = n * 16 + lr;
            bfr[n] = *(const bf16x8*)(gWb + rw * 128 + (kb ^ ((rw & 7) << 4)));
        }
        #pragma unroll
        for (int m = 0; m < 4; ++m)
            #pragma unroll
            for (int n = 0; n < 2; ++n)
                accB[m][n] = __builtin_amdgcn_mfma_f32_16x16x32_bf16(af[m], bfr[n], accB[m][n], 0, 0, 0);
    }
    __syncthreads();  // S3

    #pragma unroll
    for (int m = 0; m < 4; ++m)
        #pragma unroll
        for (int n = 0; n < 2; ++n)
            #pragma unroll
            for (int rr = 0; rr < 4; ++rr)
                smsg[(band + m * 16 + lk * 4 + rr) * 33 + n * 16 + lr] = f2bf(accB[m][n][rr]);
    sdst[tid] = d;
    if (tid == 0) { sdst[256] = dn_; sdst[257] = dp_; }
    __syncthreads();  // S4a

    const bool leader = (p < E) && (tid == 0 || sdst[tid - 1] != d);
    wmaskS[wv] = __ballot(leader);
    __syncthreads();  // S4b

    int nruns = __popcll(wmaskS[0]) + __popcll(wmaskS[1]) + __popcll(wmaskS[2]) + __popcll(wmaskS[3]);
    if (leader) {
        int before = __popcll(wmaskS[wv] & ((1ULL << lane) - 1));
        for (int w = 0; w < wv; ++w) before += __popcll(wmaskS[w]);
        rstart[before] = tid;
    }
    const int vcnt = (E - base < 256) ? (E - base) : 256;
    if (tid == 0) rstart[nruns] = vcnt;
    __syncthreads();  // S5

    const int sPrev = sdst[257];
    const int ntask = nruns * 32;
    for (int task = tid; task < ntask; task += 256) {
        const int run = task >> 5, c = task & 31;
        const int rs = rstart[run], re = rstart[run + 1];
        const int dd = sdst[rs];
        float acc = 0.0f;
        for (int qq = rs; qq < re; ++qq) acc += bf2f(smsg[qq * 33 + c]);
        const bool gs = (rs > 0) || (base == 0) || (sPrev != dd);
        const bool ge = (re < 256) || (sdst[256] != dd);
        if (gs && ge) {
            ((unsigned short*)e_t)[(size_t)dd * 32 + c] = f2bf(acc);
        } else {
            unsigned int* a32 = e_t + (size_t)dd * 16 + (c >> 1);
            const int sh = (c & 1) * 16;
            unsigned int old = *a32;
            while (true) {
                float cur2 = bf2f((old >> sh) & 0xffffu);
                unsigned int nb = f2bf(cur2 + acc);
                unsigned int nv = (old & ~(0xffffu << sh)) | (nb << sh);
                unsigned int prev = atomicCAS(a32, old, nv);
                if (prev == old) break;
                old = prev;
            }
        }
    }
}

// ---------------- stage 2: MFMA MLP1 + task-parallel reduce -> h (f32) -----

__global__ __launch_bounds__(256) void k_msg1_agg(
    const float* __restrict__ x1f, const uint4* __restrict__ x1b,
    const unsigned int* __restrict__ e_t,
    const uint2* __restrict__ ord, const unsigned char* __restrict__ wimg,
    float* __restrict__ h, int E, int NB2, int use_bf16)
{
    __shared__ __align__(16) unsigned char sBuf[32768];
    unsigned short* smsg = (unsigned short*)sBuf;
    int* sdst = (int*)(sBuf + 16896);
    int* rstart = (int*)(sBuf + 16896 + 1032);
    unsigned long long* wmaskS = (unsigned long long*)(sBuf + 16896 + 1032 + 1032);

    const int tid = threadIdx.x;
    const int base = blockIdx.x * 256, p = base + tid;

    int e = 0, s = 0, d = -1, dp_ = -1, dn_ = -1;
    if (p < E) {
        uint2 o = ord[p];
        e = (int)(o.x & 0x1FFFFFu); s = (int)(o.y & 0xFFFFFu);
        d = (((int)(o.y >> 20) - NB2) << 7) + (int)(o.x >> 21);
    }
    if (tid == 0) {
        if (base > 0) { uint2 o = ord[base - 1]; dp_ = (((int)(o.y >> 20) - NB2) << 7) + (int)(o.x >> 21); }
        if (base + 256 < E) { uint2 o = ord[base + 256]; dn_ = (((int)(o.y >> 20) - NB2) << 7) + (int)(o.x >> 21); }
    }

    // stage input row: [x1[s](32ch), e_t[e](32ch bf16)]
    {
        uint4 ch[8];
        if (use_bf16) {
            const uint4* xr = x1b + (size_t)s * 4;
            #pragma unroll
            for (int c = 0; c < 4; ++c) ch[c] = xr[c];
        } else {
            const float4* xs = (const float4*)(x1f + (size_t)s * 32);
            #pragma unroll
            for (int c = 0; c < 4; ++c) {
                float4 a = xs[2 * c], b = xs[2 * c + 1];
                ch[c].x = pack2(a.x, a.y); ch[c].y = pack2(a.z, a.w);
                ch[c].z = pack2(b.x, b.y); ch[c].w = pack2(b.z, b.w);
            }
        }
        const uint4* er = (const uint4*)(e_t + (size_t)e * 16);
        #pragma unroll
        for (int c = 0; c < 4; ++c) ch[4 + c] = er[c];
        #pragma unroll
        for (int c = 0; c < 8; ++c)
            *(uint4*)(sBuf + swz(tid, c * 16)) = ch[c];
    }
    __syncthreads();  // S1

    const int lane = tid & 63, wv = tid >> 6;
    const int lr = lane & 15, lk = lane >> 4;
    const int band = wv * 64;
    const unsigned char* gWa = wimg;
    const unsigned char* gWb = wimg + 8192;
    const float* gba = (const float*)(wimg + 12288);
    const float* gbb = (const float*)(wimg + 12544);

    f32x4 accA[4][4];
    #pragma unroll
    for (int n = 0; n < 4; ++n) {
        float bv = gba[n * 16 + lr];
        #pragma unroll
        for (int m = 0; m < 4; ++m) accA[m][n] = (f32x4){bv, bv, bv, bv};
    }
    #pragma unroll
    for (int ks = 0; ks < 2; ++ks) {
        const int kb = ks * 64 + lk * 16;
        bf16x8 af[4], bfr[4];
        #pragma unroll
        for (int m = 0; m < 4; ++m)
            af[m] = *(const bf16x8*)(sBuf + swz(band + m * 16 + lr, kb));
        #pragma unroll
        for (int n = 0; n < 4; ++n) {
            int rw = n * 16 + lr;
            bfr[n] = *(const bf16x8*)(gWa + rw * 128 + (kb ^ ((rw & 7) << 4)));
        }
        #pragma unroll
        for (int m = 0; m < 4; ++m)
            #pragma unroll
            for (int n = 0; n < 4; ++n)
                accA[m][n] = __builtin_amdgcn_mfma_f32_16x16x32_bf16(af[m], bfr[n], accA[m][n], 0, 0, 0);
    }
    #pragma unroll
    for (int m = 0; m < 4; ++m)
        #pragma unroll
        for (int n = 0; n < 4; ++n)
            #pragma unroll
            for (int rr = 0; rr < 4; ++rr) {
                int grow = band + m * 16 + lk * 4 + rr;
                int cb = 2 * (n * 16 + lr);
                *(unsigned short*)(sBuf + swz(grow, cb)) = f2bf(fmaxf(accA[m][n][rr], 0.0f));
            }

    f32x4 accB[4][2];
    #pragma unroll
    for (int n = 0; n < 2; ++n) {
        float bv = gbb[n * 16 + lr];
        #pragma unroll
        for (int m = 0; m < 4; ++m) accB[m][n] = (f32x4){bv, bv, bv, bv};
    }
    #pragma unroll
    for (int ks = 0; ks < 2; ++ks) {
        const int kb = ks * 64 + lk * 16;
        bf16x8 af[4], bfr[2];
        #pragma unroll
        for (int m = 0; m < 4; ++m)
            af[m] = *(const bf16x8*)(sBuf + swz(band + m * 16 + lr, kb));
        #pragma unroll
        for (int n = 0; n < 2; ++n) {
            int rw = n * 16 + lr;
            bfr[n] = *(const bf16x8*)(gWb + rw * 128 + (kb ^ ((rw & 7) << 4)));
        }
        #pragma unroll
        for (int m = 0; m < 4; ++m)
            #pragma unroll
            for (int n = 0; n < 2; ++n)
                accB[m][n] = __builtin_amdgcn_mfma_f32_16x16x32_bf16(af[m], bfr[n], accB[m][n], 0, 0, 0);
    }
    __syncthreads();  // S3

    #pragma unroll
    for (int m = 0; m < 4; ++m)
        #pragma unroll
        for (int n = 0; n < 2; ++n)
            #pragma unroll
            for (int rr = 0; rr < 4; ++rr)
                smsg[(band + m * 16 + lk * 4 + rr) * 33 + n * 16 + lr] = f2bf(accB[m][n][rr]);
    sdst[tid] = d;
    if (tid == 0) { sdst[256] = dn_; sdst[257] = dp_; }
    __syncthreads();  // S4a

    const bool leader = (p < E) && (tid == 0 || sdst[tid - 1] != d);
    wmaskS[wv] = __ballot(leader);
    __syncthreads();  // S4b

    int nruns = __popcll(wmaskS[0]) + __popcll(wmaskS[1]) + __popcll(wmaskS[2]) + __popcll(wmaskS[3]);
    if (leader) {
        int before = __popcll(wmaskS[wv] & ((1ULL << lane) - 1));
        for (int w = 0; w < wv; ++w) before += __popcll(wmaskS[w]);
        rstart[before] = tid;
    }
    const int vcnt = (E - base < 256) ? (E - base) : 256;
    if (tid == 0) rstart[nruns] = vcnt;
    __syncthreads();  // S5

    const int sPrev = sdst[257];
    const int ntask = nruns * 32;
    for (int task = tid; task < ntask; task += 256) {
        const int run = task >> 5, c = task & 31;
        const int rs = rstart[run], re = rstart[run + 1];
        const int dd = sdst[rs];
        float acc = 0.0f;
        for (int qq = rs; qq < re; ++qq) acc += bf2f(smsg[qq * 33 + c]);
        const bool gs = (rs > 0) || (base == 0) || (sPrev != dd);
        const bool ge = (re < 256) || (sdst[256] != dd);
        if (gs && ge) h[(size_t)dd * 32 + c] = acc;
        else atomicAdd(h + (size_t)dd * 32 + c, acc);
    }
}

// ---------------- stage 3: pool per graph (batch is sorted) ----------------

__device__ __forceinline__ int lower_bound_i(const int* a, int n, int key) {
    int lo = 0, hi = n;
    while (lo < hi) {
        int mid = (lo + hi) >> 1;
        if (a[mid] < key) lo = mid + 1; else hi = mid;
    }
    return lo;
}

__global__ __launch_bounds__(256) void k_pool(const float* __restrict__ h,
                                              const int* __restrict__ batch,
                                              float* __restrict__ out, int N1) {
    const int g = blockIdx.x;
    const int lo = lower_bound_i(batch, N1, g);
    const int hi = lower_bound_i(batch, N1, g + 1);
    const int tid = threadIdx.x;
    const int c = tid & 31, rg = tid >> 5;
    float acc = 0.0f;
    for (int n = lo + rg; n < hi; n += 8) acc += h[(size_t)n * 32 + c];
    __shared__ float red[256];
    red[tid] = acc;
    __syncthreads();
    for (int off = 128; off >= 32; off >>= 1) {
        if (tid < off) red[tid] += red[tid + off];
        __syncthreads();
    }
    if (tid < 32) out[g * 32 + tid] = red[tid] * 0.5f;
}

// ---------------------------------------------------------------------------

extern "C" void kernel_launch(void* const* d_in, const int* in_sizes, int n_in,
                              void* d_out, int out_size, void* d_ws, size_t ws_size,
                              hipStream_t stream) {
    const float* x1  = (const float*)d_in[0];
    const float* x2  = (const float*)d_in[1];
    const int*   ei1 = (const int*)d_in[2];
    const int*   ei2 = (const int*)d_in[3];
    const int*   xb  = (const int*)d_in[4];
    const float* ea2 = (const float*)d_in[5];
    const float* W2a = (const float*)d_in[6];
    const float* b2a = (const float*)d_in[7];
    const float* W2b = (const float*)d_in[8];
    const float* b2b = (const float*)d_in[9];
    const float* W1a = (const float*)d_in[10];
    const float* b1a = (const float*)d_in[11];
    const float* W1b = (const float*)d_in[12];
    const float* b1b = (const float*)d_in[13];

    const int N1 = in_sizes[0] / 32;   // 20000
    const int E1 = in_sizes[2] / 2;    // 640000
    const int E2 = in_sizes[3] / 2;    // 1280000
    const int N2 = in_sizes[1] / 32;   // 640000 (== E1)
    const int Etot = E2 + E1;

    const int NB2 = (N2 + 2047) >> 11;  // 313
    const int NB1 = (N1 + 127) >> 7;    // 157
    const int NBT = NB2 + NB1;          // 470

    const size_t sz_wpack = 25600;
    const size_t sz_cur   = (size_t)NBT * CURSTRIDE * 4;
    const size_t sz_et    = (size_t)N2 * 64;
    const size_t sz_h     = (size_t)N1 * 128;
    const size_t sz_ord   = (size_t)Etot * 8;
    const size_t sz_mid   = (size_t)NBT * CAP * 8;
    const size_t regA     = (sz_mid > sz_et + sz_h) ? sz_mid : (sz_et + sz_h);
    const size_t sz_x2b   = (size_t)N2 * 64;
    const size_t sz_x1b   = (size_t)N1 * 64;
    const size_t need_x   = sz_ord + regA + sz_x2b + sz_x1b + sz_wpack + sz_cur;

    const int use_bf16 = (ws_size >= need_x) ? 1 : 0;

    char* w = (char*)d_ws;
    uint2* ord = (uint2*)w;            w += sz_ord;
    char* regionA = w;                 w += regA;
    uint4* x2b = (uint4*)w;            if (use_bf16) w += sz_x2b;
    uint4* x1b = (uint4*)w;            if (use_bf16) w += sz_x1b;
    unsigned char* wpack = (unsigned char*)w;  w += sz_wpack;
    int* cur = (int*)w;

    unsigned int* e_t = (unsigned int*)regionA;
    float* h = (float*)(regionA + sz_et);
    uint2* mid = (uint2*)regionA;

    const int NBB = (Etot + EPB - 1) / EPB;
    const long xn2 = use_bf16 ? (long)N2 * 4 : 0;
    const long xn1 = use_bf16 ? (long)N1 * 4 : 0;

    // 1) weights + zero cursors
    k_prep0<<<2, 256, 0, stream>>>(W2a, b2a, W2b, b2b, W1a, b1a, W1b, b1b,
                                   wpack, cur, NBT * CURSTRIDE);
    // 2) fused bucket-scatter + bf16 table cvt (x2/x1 only)
    k_bscat_cvt<<<NBB + NCVT, 256, 0, stream>>>(
        ei2, E2, ei1, E1, cur, mid, NB2, NBT, Etot, NBB,
        x2, x2b, x1, x1b, xn2, xn1);
    // 3) per-bucket CSR finalize -> 8B ord (mid dead after this)
    k_csr<<<NBT, 256, 0, stream>>>(cur, mid, ord, NB2, E2);
    // 4) zero e_t + h (contiguous in regionA)
    hipMemsetAsync(regionA, 0, sz_et + sz_h, stream);
    // 5) stage 1 (ea2 gathered directly as f32: same 64B sector count as bf16)
    k_msg2_agg<<<(E2 + 255) / 256, 256, 0, stream>>>(
        x2, x2b, ea2, ord, wpack, e_t, E2, use_bf16);
    // 6) stage 2
    k_msg1_agg<<<(E1 + 255) / 256, 256, 0, stream>>>(
        x1, x1b, e_t, ord + E2, wpack + 12672, h, E1, NB2, use_bf16);
    // 7) pool
    k_pool<<<NUM_GRAPHS, 256, 0, stream>>>(h, xb, (float*)d_out, N1);
}